// Round 3
// baseline (294.186 us; speedup 1.0000x reference)
//
#include <hip/hip_runtime.h>
#include <math.h>

#define DEV __device__ __forceinline__

// ---------------- graph constants ----------------
constexpr int ESRC[36] = {0,1,2,3,4,5,6,7,8,9,10,11,12,13,14,15,16,17,18,1,2,3,4,5,6,7,8,9,10,11,12,13,14,15,16,17};
constexpr int EDST[36] = {1,2,3,4,5,6,7,8,9,10,11,12,13,14,15,16,17,18,17,0,1,2,3,4,5,6,7,8,9,10,11,12,13,14,15,16};
constexpr int SSRC[55] = {0,1,2,3,4,5,6,7,8,9,10,11,12,13,14,15,16,17,18,1,2,3,4,5,6,7,8,9,10,11,12,13,14,15,16,17,
                          0,1,2,3,4,5,6,7,8,9,10,11,12,13,14,15,16,17,18};
constexpr int SDST[55] = {1,2,3,4,5,6,7,8,9,10,11,12,13,14,15,16,17,18,17,0,1,2,3,4,5,6,7,8,9,10,11,12,13,14,15,16,
                          0,1,2,3,4,5,6,7,8,9,10,11,12,13,14,15,16,17,18};
constexpr float DINV[19] = {0.5773502691896258f,0.5f,0.5f,0.5f,0.5f,0.5f,0.5f,0.5f,0.5f,0.5f,
                            0.5f,0.5f,0.5f,0.5f,0.5f,0.5f,0.5f,0.5f,0.5773502691896258f};

// ---------------- workspace layout (float offsets) ----------------
constexpr int WS_PH  = 0;        // 4*19*1000 = 76000 gat hh partials (aliases dead C1 after K2)
constexpr int WS_C1  = 0;        // 32*63*63 = 127008 (dead after K2)
constexpr int WS_C2  = 127008;   // 32*30*30 = 28800
constexpr int WS_V   = 155808;   // 6272
constexpr int WS_FC0 = 162080;   // 6000 (fc0 partial, k-half 0; NO bias)
constexpr int WS_N1  = 168080;   // 100
constexpr int WS_N2  = 168180;   // 100
constexpr int WS_HA  = 168280;   // 19*1000
constexpr int WS_HB  = 187280;   // 19*1000
constexpr int WS_AGA = 206280;   // 19*1000 (dead after K2) -> fc0 partial half 1
constexpr int WS_FC0B= 206280;   // 6000 (fc0 partial, k-half 1; aliases AGA, dead by K4)
constexpr int WS_GV  = 263280;   // 1000
constexpr int WS_N3  = 264280;   // 100
constexpr int WS_PB  = 264384;   // 76000 sage partials ping
constexpr int WS_PC  = 340384;   // 76000 sage partials pong  (end 416384 fl = 1.67 MB)

DEV float wredsum(float v){
  #pragma unroll
  for (int o = 32; o; o >>= 1) v += __shfl_xor(v, o);
  return v;
}
DEV float d4(float4 a, float4 b){ return a.x*b.x + a.y*b.y + a.z*b.z + a.w*b.w; }
DEV float4 add4(float4 a, float4 b, float4 c){
  return make_float4(a.x+b.x+c.x, a.y+b.y+c.y, a.z+b.z+c.z, a.w+b.w+c.w);
}

// ============================================================================
// SAGE split matmul (unchanged from R2)
// ============================================================================
template<int MODE>
DEV void sage_split(int blk, int tid, float* sm,
                    const float* __restrict__ hin, const float* __restrict__ pin,
                    const float* __restrict__ pbias, const float* __restrict__ agin,
                    const float* __restrict__ lw, const float* __restrict__ rw,
                    float* __restrict__ pout)
{
  const int cg = blk >> 2, kq = blk & 3;
  const int kb = kq*256;
  const int cntf = (kq < 3) ? 256 : 232;
  const int cnt4 = cntf >> 2;
  float* hS = sm;            // [19][256]
  float* aS = sm + 19*256;   // [19][256]
  if (MODE == 2){
    for (int c = tid; c < 19*256; c += 256){
      const int n = c >> 8, j = c & 255;
      if (j < cntf){
        const int i = kb + j;
        const float v = pin[n*1000+i] + pin[(19+n)*1000+i] + pin[(38+n)*1000+i]
                      + pin[(57+n)*1000+i] + pbias[i];
        hS[c] = fmaxf(v, 0.f);
      }
    }
  } else {
    for (int c = tid; c < 19*64; c += 256){
      const int n = c >> 6, j = c & 63;
      if (j < cnt4)
        ((float4*)hS)[n*64 + j] = *(const float4*)(hin + n*1000 + kb + 4*j);
    }
  }
  if (MODE == 0){
    for (int c = tid; c < 19*64; c += 256){
      const int n = c >> 6, j = c & 63;
      if (j < cnt4)
        ((float4*)aS)[n*64 + j] = *(const float4*)(agin + n*1000 + kb + 4*j);
    }
  }
  __syncthreads();
  if (MODE != 0){
    if (tid < cntf){
      float hv[19];
      #pragma unroll
      for (int n=0;n<19;++n) hv[n] = hS[n*256 + tid];
      float ag[19];
      #pragma unroll
      for (int n=0;n<19;++n) ag[n] = 0.f;
      #pragma unroll
      for (int e=0;e<36;++e) ag[EDST[e]] += hv[ESRC[e]];
      #pragma unroll
      for (int n=0;n<19;++n) aS[n*256 + tid] = ag[n];
    }
    __syncthreads();
  }
  const int lane = tid & 63, wv = tid >> 6;
  const int i0 = cg*8 + 2*wv, i1 = i0 + 1;
  float acc0[19], acc1[19];
  #pragma unroll
  for (int n=0;n<19;++n){ acc0[n]=0.f; acc1[n]=0.f; }
  if (lane < cnt4){
    const float4 wl0 = *((const float4*)(lw + i0*1000) + kq*64 + lane);
    const float4 wl1 = *((const float4*)(lw + i1*1000) + kq*64 + lane);
    const float4 wr0 = *((const float4*)(rw + i0*1000) + kq*64 + lane);
    const float4 wr1 = *((const float4*)(rw + i1*1000) + kq*64 + lane);
    const float4* h4 = (const float4*)hS;
    const float4* a4 = (const float4*)aS;
    #pragma unroll
    for (int n=0;n<19;++n){
      const float4 hv = h4[n*64+lane], av = a4[n*64+lane];
      acc0[n] = d4(wl0,av) + d4(wr0,hv);
      acc1[n] = d4(wl1,av) + d4(wr1,hv);
    }
  }
  #pragma unroll
  for (int n=0;n<19;++n){ acc0[n]=wredsum(acc0[n]); acc1[n]=wredsum(acc1[n]); }
  if (lane == 0){
    #pragma unroll
    for (int n=0;n<19;++n){
      pout[(kq*19+n)*1000 + i0] = acc0[n];
      pout[(kq*19+n)*1000 + i1] = acc1[n];
    }
  }
}

// ============================================================================
// GAT/GCN split matmul (unchanged from R2)
// ============================================================================
template<int MODE>
DEV void gatmat_split(int blk, int tid, float* sm,
                      const float* __restrict__ hin, const float* __restrict__ pin,
                      const float* __restrict__ pbias,
                      const float* __restrict__ W, float* __restrict__ pout)
{
  const int cg = blk >> 2, kq = blk & 3;
  const int kb = kq*256;
  const int cntf = (kq < 3) ? 256 : 232;
  const int cnt4 = cntf >> 2;
  float* hS = sm;
  if (MODE == 2){
    for (int c = tid; c < 19*256; c += 256){
      const int n = c >> 8, j = c & 255;
      if (j < cntf){
        const int i = kb + j;
        const float v = pin[n*1000+i] + pin[(19+n)*1000+i] + pin[(38+n)*1000+i]
                      + pin[(57+n)*1000+i] + pbias[i];
        hS[c] = fmaxf(v, 0.f);
      }
    }
  } else {
    for (int c = tid; c < 19*64; c += 256){
      const int n = c >> 6, j = c & 63;
      if (j < cnt4)
        ((float4*)hS)[n*64 + j] = *(const float4*)(hin + n*1000 + kb + 4*j);
    }
  }
  __syncthreads();
  const int lane = tid & 63, wv = tid >> 6;
  const int i0 = cg*8 + 2*wv, i1 = i0 + 1;
  float acc0[19], acc1[19];
  #pragma unroll
  for (int n=0;n<19;++n){ acc0[n]=0.f; acc1[n]=0.f; }
  if (lane < cnt4){
    const float4 w0 = *((const float4*)(W + i0*1000) + kq*64 + lane);
    const float4 w1 = *((const float4*)(W + i1*1000) + kq*64 + lane);
    const float4* h4 = (const float4*)hS;
    #pragma unroll
    for (int n=0;n<19;++n){
      const float4 hv = h4[n*64+lane];
      acc0[n] = d4(w0,hv);
      acc1[n] = d4(w1,hv);
    }
  }
  #pragma unroll
  for (int n=0;n<19;++n){ acc0[n]=wredsum(acc0[n]); acc1[n]=wredsum(acc1[n]); }
  if (lane == 0){
    #pragma unroll
    for (int n=0;n<19;++n){
      pout[(kq*19+n)*1000 + i0] = acc0[n];
      pout[(kq*19+n)*1000 + i1] = acc1[n];
    }
  }
}

// ---- GAT finisher (unchanged from R2) ----
DEV void gat_fin(int blk, int tid, float* smf, const float* __restrict__ ph,
                 const float* __restrict__ as_, const float* __restrict__ ad_,
                 const float* __restrict__ bias, float* __restrict__ hout)
{
  float* s_es = smf; float* s_ed = smf+19; float* s_w = smf+38;
  float* s_m = smf+93; float* s_den = smf+112; float* s_part = smf+131; // 152
  const int lane = tid & 63, wv = tid >> 6;
  float es[19], ed[19];
  #pragma unroll
  for (int n=0;n<19;++n){ es[n]=0.f; ed[n]=0.f; }
  for (int k = tid; k < 1000; k += 256){
    const float as = as_[k], ad = ad_[k];
    #pragma unroll
    for (int n=0;n<19;++n){
      const float hv = ph[n*1000+k] + ph[(19+n)*1000+k] + ph[(38+n)*1000+k] + ph[(57+n)*1000+k];
      es[n] += hv*as; ed[n] += hv*ad;
    }
  }
  #pragma unroll
  for (int n=0;n<19;++n){ es[n]=wredsum(es[n]); ed[n]=wredsum(ed[n]); }
  if (lane == 0){
    #pragma unroll
    for (int n=0;n<19;++n){ s_part[wv*38+n]=es[n]; s_part[wv*38+19+n]=ed[n]; }
  }
  __syncthreads();
  if (tid < 38){
    const float s = s_part[tid] + s_part[38+tid] + s_part[76+tid] + s_part[114+tid];
    if (tid < 19) s_es[tid] = s; else s_ed[tid-19] = s;
  }
  __syncthreads();
  if (tid < 55){
    float e = s_es[SSRC[tid]] + s_ed[SDST[tid]];
    s_w[tid] = e > 0.f ? e : 0.2f*e;
  }
  __syncthreads();
  if (tid < 19){
    float m = -1e30f;
    #pragma unroll
    for (int e=0;e<55;++e) if (SDST[e]==tid) m = fmaxf(m, s_w[e]);
    float den = 0.f;
    #pragma unroll
    for (int e=0;e<55;++e) if (SDST[e]==tid) den += expf(s_w[e]-m);
    s_m[tid]=m; s_den[tid]=den;
  }
  __syncthreads();
  if (tid < 55) s_w[tid] = expf(s_w[tid]-s_m[SDST[tid]]) / s_den[SDST[tid]];
  __syncthreads();
  const int i = blk*256 + tid;
  if (i < 1000){
    float hv[19];
    #pragma unroll
    for (int n=0;n<19;++n)
      hv[n] = ph[n*1000+i] + ph[(19+n)*1000+i] + ph[(38+n)*1000+i] + ph[(57+n)*1000+i];
    float acc[19];
    #pragma unroll
    for (int n=0;n<19;++n) acc[n]=0.f;
    #pragma unroll
    for (int e=0;e<55;++e) acc[SDST[e]] += s_w[e]*hv[SSRC[e]];
    const float bi = bias[i];
    #pragma unroll
    for (int n=0;n<19;++n) hout[n*1000+i] = fmaxf(acc[n]+bi, 0.f);
  }
}

// =================== K1: conv1 + sage1a(+agg) + state MLP ===================
__global__ __launch_bounds__(256) void k_ac_1(
    const float* __restrict__ x, const float* __restrict__ c1w, const float* __restrict__ c1b,
    const float* __restrict__ xg, const float* __restrict__ s1alw, const float* __restrict__ s1alb,
    const float* __restrict__ s1arw,
    const float* __restrict__ stt, const float* __restrict__ fc2w, const float* __restrict__ fc2b,
    const float* __restrict__ fc3w, const float* __restrict__ fc3b,
    float* __restrict__ ws)
{
  const int b = blockIdx.x, t = threadIdx.x;
  if (b < 497){
    const int idx = b*256 + t;
    if (idx < 127008){
      const int oc = idx/3969, r = idx - oc*3969, oy = r/63, ox = r - oy*63;
      const float* wp = c1w + oc*25;
      float acc = c1b[oc];
      #pragma unroll
      for (int ky=0;ky<5;++ky){
        const int iy = oy*2 - 1 + ky;
        if ((unsigned)iy < 128u){
          #pragma unroll
          for (int kx=0;kx<5;++kx){
            const int ix = ox*2 - 1 + kx;
            if ((unsigned)ix < 128u) acc += x[iy*128+ix]*wp[ky*5+kx];
          }
        }
      }
      ws[WS_C1+idx] = fmaxf(acc, 0.f);
    }
  } else if (b < 501){
    const int i = (b-497)*256 + t;
    if (i < 1000){
      float xv[19];
      #pragma unroll
      for (int n=0;n<19;++n) xv[n] = xg[n];
      float ag[19];
      #pragma unroll
      for (int n=0;n<19;++n) ag[n]=0.f;
      #pragma unroll
      for (int e=0;e<36;++e) ag[EDST[e]] += xv[ESRC[e]];
      const float lwv=s1alw[i], lbv=s1alb[i], rwv=s1arw[i];
      float hc[19];
      #pragma unroll
      for (int n=0;n<19;++n){
        hc[n] = fmaxf(lwv*ag[n] + lbv + rwv*xv[n], 0.f);
        ws[WS_HA+n*1000+i] = hc[n];
      }
      #pragma unroll
      for (int n=0;n<19;++n){
        float a=0.f;
        #pragma unroll
        for (int e=0;e<36;++e) if (EDST[e]==n) a += hc[ESRC[e]];
        ws[WS_AGA+n*1000+i] = a;
      }
    }
  } else {
    __shared__ float s1[100];
    if (t < 100){
      float acc = fc2b[t];
      #pragma unroll
      for (int k=0;k<20;++k) acc += fc2w[t*20+k]*stt[k];
      s1[t] = acc;
    }
    __syncthreads();
    if (t < 100){
      float acc = fc3b[t];
      for (int k=0;k<100;++k) acc += fc3w[t*100+k]*s1[k];
      ws[WS_N2+t] = acc;
    }
  }
}

// =================== K2: conv2 (LDS, 128 blocks) + sage1b-split ===================
__global__ __launch_bounds__(256) void k_ac_2(
    const float* __restrict__ c2w, const float* __restrict__ c2b,
    const float* __restrict__ s1blw, const float* __restrict__ s1blb, const float* __restrict__ s1brw,
    float* __restrict__ ws)
{
  __shared__ float sm[9728];
  const int b = blockIdx.x, t = threadIdx.x;
  if (b < 128){
    const int oc = b >> 2, q = b & 3;
    const int r0 = q*16;
    const int nout = (q < 3) ? 240 : 180;
    float* buf0 = sm; float* buf1 = sm + 4788;
    float rv[19];
    #pragma unroll
    for (int u=0; u<19; ++u){
      const int c = t + u*256; float v = 0.f;
      if (c < 4788){
        const int p = c/1197, r = c - p*1197, lr = r/63, xx = r - lr*63;
        const int iy = r0 + lr;
        if (iy < 63) v = ws[WS_C1 + p*3969 + iy*63 + xx];
      }
      rv[u] = v;
    }
    #pragma unroll
    for (int u=0; u<19; ++u){ const int c = t+u*256; if (c<4788) buf0[c]=rv[u]; }
    __syncthreads();
    const int oy_l = t/30, ox = t - oy_l*30;
    float acc = (t < nout) ? c2b[oc] : 0.f;
    for (int g=0; g<8; ++g){
      float* cur = (g&1) ? buf1 : buf0;
      if (g < 7){
        #pragma unroll
        for (int u=0; u<19; ++u){
          const int c = t + u*256; float v = 0.f;
          if (c < 4788){
            const int p = c/1197, r = c - p*1197, lr = r/63, xx = r - lr*63;
            const int iy = r0 + lr;
            if (iy < 63) v = ws[WS_C1 + (4*(g+1)+p)*3969 + iy*63 + xx];
          }
          rv[u] = v;
        }
      }
      if (t < nout){
        #pragma unroll
        for (int p=0;p<4;++p){
          const float* wp = c2w + (oc*32 + 4*g + p)*25;
          const float* ip = cur + p*1197 + (2*oy_l)*63 + 2*ox;
          #pragma unroll
          for (int ky=0;ky<5;++ky)
            #pragma unroll
            for (int kx=0;kx<5;++kx)
              acc += ip[ky*63+kx]*wp[ky*5+kx];
        }
      }
      if (g < 7){
        __syncthreads();
        float* nxt = (g&1) ? buf0 : buf1;
        #pragma unroll
        for (int u=0; u<19; ++u){ const int c = t+u*256; if (c<4788) nxt[c]=rv[u]; }
        __syncthreads();
      }
    }
    if (t < nout){
      const int oy = q*8 + oy_l;
      ws[WS_C2 + oc*900 + oy*30 + ox] = fmaxf(acc, 0.f);
    }
  } else {
    sage_split<0>(b-128, t, sm, ws+WS_HA, nullptr, nullptr, ws+WS_AGA, s1blw, s1brw, ws+WS_PB);
  }
}

// =================== K3: conv3 (LDS, 32 blocks) + gat2mm-split ===================
__global__ __launch_bounds__(256) void k_ac_3(
    const float* __restrict__ c3w, const float* __restrict__ c3b,
    const float* __restrict__ s1blb, const float* __restrict__ g2w,
    float* __restrict__ ws)
{
  __shared__ float sm[7200];
  const int b = blockIdx.x, t = threadIdx.x;
  if (b < 32){
    const int oc = b;
    float* buf0 = sm; float* buf1 = sm + 3600;
    float rv[15];
    #pragma unroll
    for (int u=0; u<15; ++u){
      const int c = t + u*256;
      rv[u] = (c < 3600) ? ws[WS_C2 + c] : 0.f;
    }
    #pragma unroll
    for (int u=0; u<15; ++u){ const int c = t+u*256; if (c<3600) buf0[c]=rv[u]; }
    __syncthreads();
    const int oy = t/14, ox = t - oy*14;
    float acc = (t < 196) ? c3b[oc] : 0.f;
    for (int g=0; g<8; ++g){
      float* cur = (g&1) ? buf1 : buf0;
      if (g < 7){
        #pragma unroll
        for (int u=0; u<15; ++u){
          const int c = t + u*256;
          rv[u] = (c < 3600) ? ws[WS_C2 + (g+1)*3600 + c] : 0.f;
        }
      }
      if (t < 196){
        #pragma unroll
        for (int p=0;p<4;++p){
          const float* wp = c3w + (oc*32 + 4*g + p)*25;
          const float* ip = cur + p*900;
          #pragma unroll
          for (int ky=0;ky<5;++ky){
            const int iy = oy*2 - 1 + ky;
            if ((unsigned)iy < 30u){
              #pragma unroll
              for (int kx=0;kx<5;++kx){
                const int ix = ox*2 - 1 + kx;
                if ((unsigned)ix < 30u) acc += ip[iy*30+ix]*wp[ky*5+kx];
              }
            }
          }
        }
      }
      if (g < 7){
        __syncthreads();
        float* nxt = (g&1) ? buf0 : buf1;
        #pragma unroll
        for (int u=0; u<15; ++u){ const int c = t+u*256; if (c<3600) nxt[c]=rv[u]; }
        __syncthreads();
      }
    }
    if (t < 196) ws[WS_V + oc*196 + t] = acc;  // no relu on conv3
  } else {
    gatmat_split<2>(b-32, t, sm, nullptr, ws+WS_PB, s1blb, g2w, ws+WS_PH);
  }
}

// =================== K4: fc0 (K-split x2, batched loads) + gat2fin ===================
// block b<3000: rq=b>>1 (4 rows), half=b&1 (784 f4 of K). Wave = one row-half.
// Stage v-half (12.5 KB) in LDS; wave loads all 12 f4 weights into regs first
// (12 KB in flight) then FMAs. Partial (no bias) -> WS_FC0 / WS_FC0B.
__global__ __launch_bounds__(256) void k_ac_4(
    const float* __restrict__ fc0w, const float* __restrict__ fc0b,
    const float* __restrict__ g2as, const float* __restrict__ g2ad, const float* __restrict__ g2b,
    float* __restrict__ ws)
{
  __shared__ float sm[3136];   // 784 float4 = 12544 B
  const int b = blockIdx.x, t = threadIdx.x;
  if (b < 3000){
    const int rq = b >> 1, half = b & 1;
    const int lane = t & 63, wv = t >> 6;
    // stage v half
    float4* smf4 = (float4*)sm;
    const float4* vsrc = (const float4*)(ws + WS_V) + half*784;
    for (int c = t; c < 784; c += 256) smf4[c] = vsrc[c];
    __syncthreads();
    const int row = rq*4 + wv;
    const float4* wr = (const float4*)(fc0w) + (size_t)row*1568 + half*784;
    // batched weight loads: 12 full + 16-lane tail, all issued before use
    float4 wreg[12];
    #pragma unroll
    for (int u=0; u<12; ++u) wreg[u] = wr[u*64 + lane];
    float4 wtail;
    if (lane < 16) wtail = wr[768 + lane];
    float acc = 0.f;
    #pragma unroll
    for (int u=0; u<12; ++u) acc += d4(wreg[u], smf4[u*64 + lane]);
    if (lane < 16) acc += d4(wtail, smf4[768 + lane]);
    acc = wredsum(acc);
    if (lane == 0){
      float* pout = ws + (half ? WS_FC0B : WS_FC0);
      pout[row] = acc;           // bias added in fc1 consumer
    }
  } else {
    gat_fin(b-3000, t, sm, ws+WS_PH, g2as, g2ad, g2b, ws+WS_HA);
  }
}

// =================== K5: fc1 (block-per-row, sums fc0 partials + bias) + sage3a-split ===================
__global__ __launch_bounds__(256) void k_ac_5(
    const float* __restrict__ fc1w, const float* __restrict__ fc1b,
    const float* __restrict__ fc0b,
    const float* __restrict__ s3alw, const float* __restrict__ s3arw,
    float* __restrict__ ws)
{
  __shared__ float sm[9728];
  const int b = blockIdx.x, t = threadIdx.x;
  if (b < 100){
    const int row = b, lane = t & 63, wv = t >> 6;
    const float4* wr = (const float4*)(fc1w + row*6000);
    const float4* p0 = (const float4*)(ws + WS_FC0);
    const float4* p1 = (const float4*)(ws + WS_FC0B);
    const float4* bb = (const float4*)fc0b;
    float acc = 0.f;
    #pragma unroll
    for (int u=0; u<6; ++u){
      const int j = t + u*256;
      if (j < 1500) acc += d4(wr[j], add4(p0[j], p1[j], bb[j]));
    }
    acc = wredsum(acc);
    if (lane == 0) sm[wv] = acc;
    __syncthreads();
    if (t == 0) ws[WS_N1+row] = sm[0]+sm[1]+sm[2]+sm[3] + fc1b[row];
  } else {
    sage_split<1>(b-100, t, sm, ws+WS_HA, nullptr, nullptr, nullptr, s3alw, s3arw, ws+WS_PB);
  }
}

// =================== K6: sage3b-split ===================
__global__ __launch_bounds__(256) void k_ac_6(
    const float* __restrict__ s3alb, const float* __restrict__ s3blw, const float* __restrict__ s3brw,
    float* __restrict__ ws)
{
  __shared__ float sm[9728];
  sage_split<2>(blockIdx.x, threadIdx.x, sm, nullptr, ws+WS_PB, s3alb, nullptr, s3blw, s3brw, ws+WS_PC);
}

// =================== K7: gat4mm-split ===================
__global__ __launch_bounds__(256) void k_ac_7(
    const float* __restrict__ s3blb, const float* __restrict__ g4w, float* __restrict__ ws)
{
  __shared__ float sm[4864];
  gatmat_split<2>(blockIdx.x, threadIdx.x, sm, nullptr, ws+WS_PC, s3blb, g4w, ws+WS_PH);
}

// =================== K8: gat4fin ===================
__global__ __launch_bounds__(256) void k_ac_8(
    const float* __restrict__ g4as, const float* __restrict__ g4ad, const float* __restrict__ g4b,
    float* __restrict__ ws)
{
  __shared__ float sm[283];
  gat_fin(blockIdx.x, threadIdx.x, sm, ws+WS_PH, g4as, g4ad, g4b, ws+WS_HB);
}

// =================== K9: gcn-split ===================
__global__ __launch_bounds__(256) void k_ac_9(
    const float* __restrict__ gw, float* __restrict__ ws)
{
  __shared__ float sm[4864];
  gatmat_split<3>(blockIdx.x, threadIdx.x, sm, ws+WS_HB, nullptr, nullptr, gw, ws+WS_PB);
}

// =================== K10: gcn finish + node-mean -> gv ===================
__global__ __launch_bounds__(256) void k_ac_10(
    const float* __restrict__ gb, float* __restrict__ ws)
{
  const int i = blockIdx.x*256 + threadIdx.x;
  if (i < 1000){
    float c[19];
    #pragma unroll
    for (int m=0;m<19;++m) c[m] = 2.f*DINV[m]*DINV[m];
    #pragma unroll
    for (int e=0;e<36;++e) c[ESRC[e]] += DINV[ESRC[e]]*DINV[EDST[e]];
    float s = gb[i];
    #pragma unroll
    for (int m=0;m<19;++m){
      const float hh = ws[WS_PB + m*1000 + i] + ws[WS_PB + (19+m)*1000 + i]
                     + ws[WS_PB + (38+m)*1000 + i] + ws[WS_PB + (57+m)*1000 + i];
      s += (c[m]*(1.f/19.f))*hh;
    }
    ws[WS_GV+i] = s;
  }
}

// =================== K11: fcg (block-per-row) ===================
__global__ __launch_bounds__(256) void k_ac_11(
    const float* __restrict__ fcgw, const float* __restrict__ fcgb, float* __restrict__ ws)
{
  __shared__ float sm[4];
  const int b = blockIdx.x, t = threadIdx.x, lane = t & 63, wv = t >> 6;
  const float4* wr = (const float4*)(fcgw + b*1000);
  const float4* vr = (const float4*)(ws + WS_GV);
  float acc = (t < 250) ? d4(wr[t], vr[t]) : 0.f;
  acc = wredsum(acc);
  if (lane == 0) sm[wv] = acc;
  __syncthreads();
  if (t == 0) ws[WS_N3+b] = sm[0]+sm[1]+sm[2]+sm[3] + fcgb[b];
}

// =================== K12: head ===================
__global__ __launch_bounds__(512) void k_ac_head(
    const float* __restrict__ fc4w, const float* __restrict__ fc4b,
    const float* __restrict__ muw, const float* __restrict__ mub,
    const float* __restrict__ ls,  const float* __restrict__ crw, const float* __restrict__ crb,
    float* __restrict__ ws, float* __restrict__ out)
{
  __shared__ float f[300];
  __shared__ float mnmx[6];
  __shared__ float feats[200];
  const int t = threadIdx.x, lane = t & 63, wv = t >> 6;
  if (t < 100)       f[t] = ws[WS_N1 + t];
  else if (t < 200)  f[t] = ws[WS_N2 + t - 100];
  else if (t < 300)  f[t] = ws[WS_N3 + t - 200];
  __syncthreads();
  if (wv < 3){
    const int base = wv*100;
    const float v  = f[base + lane];
    const float v2 = (lane < 36) ? f[base + 64 + lane] : v;
    float mn = fminf(v, v2), mx = fmaxf(v, v2);
    #pragma unroll
    for (int o=32;o;o>>=1){ mn = fminf(mn, __shfl_xor(mn,o)); mx = fmaxf(mx, __shfl_xor(mx,o)); }
    if (lane == 0){ mnmx[wv*2]=mn; mnmx[wv*2+1]=mx; }
  }
  __syncthreads();
  if (t < 300){
    const int c = t/100;
    f[t] = (f[t]-mnmx[c*2])/(mnmx[c*2+1]-mnmx[c*2]);
  }
  __syncthreads();
  for (int rr=0; rr<25; ++rr){
    const int row = wv*25 + rr;
    const float* wp = fc4w + row*300;
    float acc = 0.f;
    #pragma unroll
    for (int it=0; it<5; ++it){
      const int k = it*64 + lane;
      if (k < 300) acc += wp[k]*f[k];
    }
    acc = wredsum(acc);
    if (lane == 0) feats[row] = acc + fc4b[row];
  }
  __syncthreads();
  if (t < 12){
    const float* wp = muw + t*200;
    float a = mub[t];
    for (int k=0;k<200;++k) a += wp[k]*feats[k];
    out[t] = tanhf(a);
  } else if (t < 24){
    out[t] = expf(ls[t-12]);
  } else if (t == 24){
    float a = crb[0];
    for (int k=0;k<200;++k) a += crw[k]*feats[k];
    out[24] = a;
  }
}

extern "C" void kernel_launch(void* const* d_in, const int* in_sizes, int n_in,
                              void* d_out, int out_size, void* d_ws, size_t ws_size,
                              hipStream_t stream)
{
  (void)in_sizes; (void)n_in; (void)out_size; (void)ws_size;
  const float* x     = (const float*)d_in[0];
  const float* stt   = (const float*)d_in[1];
  const float* xg    = (const float*)d_in[2];
  const float* c1w   = (const float*)d_in[3];
  const float* c1b   = (const float*)d_in[4];
  const float* c2w   = (const float*)d_in[5];
  const float* c2b   = (const float*)d_in[6];
  const float* c3w   = (const float*)d_in[7];
  const float* c3b   = (const float*)d_in[8];
  const float* fc0w  = (const float*)d_in[9];
  const float* fc0b  = (const float*)d_in[10];
  const float* fc1w  = (const float*)d_in[11];
  const float* fc1b  = (const float*)d_in[12];
  const float* fc2w  = (const float*)d_in[13];
  const float* fc2b  = (const float*)d_in[14];
  const float* fc3w  = (const float*)d_in[15];
  const float* fc3b  = (const float*)d_in[16];
  const float* s1alw = (const float*)d_in[17];
  const float* s1alb = (const float*)d_in[18];
  const float* s1arw = (const float*)d_in[19];
  const float* s1blw = (const float*)d_in[20];
  const float* s1blb = (const float*)d_in[21];
  const float* s1brw = (const float*)d_in[22];
  const float* g2w   = (const float*)d_in[23];
  const float* g2as  = (const float*)d_in[24];
  const float* g2ad  = (const float*)d_in[25];
  const float* g2b   = (const float*)d_in[26];
  const float* s3alw = (const float*)d_in[27];
  const float* s3alb = (const float*)d_in[28];
  const float* s3arw = (const float*)d_in[29];
  const float* s3blw = (const float*)d_in[30];
  const float* s3blb = (const float*)d_in[31];
  const float* s3brw = (const float*)d_in[32];
  const float* g4w   = (const float*)d_in[33];
  const float* g4as  = (const float*)d_in[34];
  const float* g4ad  = (const float*)d_in[35];
  const float* g4b   = (const float*)d_in[36];
  const float* gcnw  = (const float*)d_in[37];
  const float* gcnb  = (const float*)d_in[38];
  const float* fcgw  = (const float*)d_in[39];
  const float* fcgb  = (const float*)d_in[40];
  const float* fc4w  = (const float*)d_in[41];
  const float* fc4b  = (const float*)d_in[42];
  const float* muw   = (const float*)d_in[43];
  const float* mub   = (const float*)d_in[44];
  const float* lsig  = (const float*)d_in[45];
  const float* crw   = (const float*)d_in[46];
  const float* crb   = (const float*)d_in[47];
  float* ws  = (float*)d_ws;
  float* out = (float*)d_out;

  k_ac_1 <<<dim3(502), dim3(256), 0, stream>>>(x, c1w, c1b, xg, s1alw, s1alb, s1arw,
                                               stt, fc2w, fc2b, fc3w, fc3b, ws);
  k_ac_2 <<<dim3(628), dim3(256), 0, stream>>>(c2w, c2b, s1blw, s1blb, s1brw, ws);
  k_ac_3 <<<dim3(532), dim3(256), 0, stream>>>(c3w, c3b, s1blb, g2w, ws);
  k_ac_4 <<<dim3(3004), dim3(256), 0, stream>>>(fc0w, fc0b, g2as, g2ad, g2b, ws);
  k_ac_5 <<<dim3(600), dim3(256), 0, stream>>>(fc1w, fc1b, fc0b, s3alw, s3arw, ws);
  k_ac_6 <<<dim3(500), dim3(256), 0, stream>>>(s3alb, s3blw, s3brw, ws);
  k_ac_7 <<<dim3(500), dim3(256), 0, stream>>>(s3blb, g4w, ws);
  k_ac_8 <<<dim3(4),   dim3(256), 0, stream>>>(g4as, g4ad, g4b, ws);
  k_ac_9 <<<dim3(500), dim3(256), 0, stream>>>(gcnw, ws);
  k_ac_10<<<dim3(4),   dim3(256), 0, stream>>>(gcnb, ws);
  k_ac_11<<<dim3(100), dim3(256), 0, stream>>>(fcgw, fcgb, ws);
  k_ac_head<<<dim3(1), dim3(512), 0, stream>>>(fc4w, fc4b, muw, mub, lsig, crw, crb, ws, out);
}

// Round 4
// 272.155 us; speedup vs baseline: 1.0810x; 1.0810x over previous
//
#include <hip/hip_runtime.h>
#include <math.h>

#define DEV __device__ __forceinline__

// ---------------- graph constants ----------------
constexpr int ESRC[36] = {0,1,2,3,4,5,6,7,8,9,10,11,12,13,14,15,16,17,18,1,2,3,4,5,6,7,8,9,10,11,12,13,14,15,16,17};
constexpr int EDST[36] = {1,2,3,4,5,6,7,8,9,10,11,12,13,14,15,16,17,18,17,0,1,2,3,4,5,6,7,8,9,10,11,12,13,14,15,16};
constexpr int SSRC[55] = {0,1,2,3,4,5,6,7,8,9,10,11,12,13,14,15,16,17,18,1,2,3,4,5,6,7,8,9,10,11,12,13,14,15,16,17,
                          0,1,2,3,4,5,6,7,8,9,10,11,12,13,14,15,16,17,18};
constexpr int SDST[55] = {1,2,3,4,5,6,7,8,9,10,11,12,13,14,15,16,17,18,17,0,1,2,3,4,5,6,7,8,9,10,11,12,13,14,15,16,
                          0,1,2,3,4,5,6,7,8,9,10,11,12,13,14,15,16,17,18};
constexpr float DINV[19] = {0.5773502691896258f,0.5f,0.5f,0.5f,0.5f,0.5f,0.5f,0.5f,0.5f,0.5f,
                            0.5f,0.5f,0.5f,0.5f,0.5f,0.5f,0.5f,0.5f,0.5773502691896258f};

// ---------------- workspace layout (float offsets) ----------------
constexpr int WS_PH  = 0;        // 4*19*1000 gat hh partials (aliases dead C1)
constexpr int WS_C1  = 0;        // 32*63*63 = 127008 (dead after K2)
constexpr int WS_C2  = 127008;   // 32*30*30 = 28800
constexpr int WS_V   = 155808;   // 6272
constexpr int WS_FC0 = 162080;   // 6000 (fc0 partial, k-half 0; NO bias)
constexpr int WS_N1  = 168080;   // 100
constexpr int WS_N2  = 168180;   // 100
constexpr int WS_HA  = 168280;   // 19*1000
constexpr int WS_HB  = 187280;   // 19*1000
constexpr int WS_AGA = 206280;   // 19*1000 (dead after K2)
constexpr int WS_FC0B= 206280;   // 6000 (fc0 partial, k-half 1; aliases AGA)
constexpr int WS_GV  = 263280;   // 1000
constexpr int WS_AL  = 264280;   // 55 alpha (temporal reuse of N3 slot, dead before k11)
constexpr int WS_N3  = 264280;   // 100 (written by k11 AFTER alpha consumed)
constexpr int WS_PB  = 264384;   // 76000 sage partials ping
constexpr int WS_PC  = 340384;   // 76000 sage partials pong

DEV float wredsum(float v){
  #pragma unroll
  for (int o = 32; o; o >>= 1) v += __shfl_xor(v, o);
  return v;
}
DEV float d4(float4 a, float4 b){ return a.x*b.x + a.y*b.y + a.z*b.z + a.w*b.w; }
DEV float4 add4(float4 a, float4 b, float4 c){
  return make_float4(a.x+b.x+c.x, a.y+b.y+c.y, a.z+b.z+c.z, a.w+b.w+c.w);
}

// ============================================================================
// SAGE split matmul (unchanged)
// ============================================================================
template<int MODE>
DEV void sage_split(int blk, int tid, float* sm,
                    const float* __restrict__ hin, const float* __restrict__ pin,
                    const float* __restrict__ pbias, const float* __restrict__ agin,
                    const float* __restrict__ lw, const float* __restrict__ rw,
                    float* __restrict__ pout)
{
  const int cg = blk >> 2, kq = blk & 3;
  const int kb = kq*256;
  const int cntf = (kq < 3) ? 256 : 232;
  const int cnt4 = cntf >> 2;
  float* hS = sm;            // [19][256]
  float* aS = sm + 19*256;   // [19][256]
  if (MODE == 2){
    for (int c = tid; c < 19*256; c += 256){
      const int n = c >> 8, j = c & 255;
      if (j < cntf){
        const int i = kb + j;
        const float v = pin[n*1000+i] + pin[(19+n)*1000+i] + pin[(38+n)*1000+i]
                      + pin[(57+n)*1000+i] + pbias[i];
        hS[c] = fmaxf(v, 0.f);
      }
    }
  } else {
    for (int c = tid; c < 19*64; c += 256){
      const int n = c >> 6, j = c & 63;
      if (j < cnt4)
        ((float4*)hS)[n*64 + j] = *(const float4*)(hin + n*1000 + kb + 4*j);
    }
  }
  if (MODE == 0){
    for (int c = tid; c < 19*64; c += 256){
      const int n = c >> 6, j = c & 63;
      if (j < cnt4)
        ((float4*)aS)[n*64 + j] = *(const float4*)(agin + n*1000 + kb + 4*j);
    }
  }
  __syncthreads();
  if (MODE != 0){
    if (tid < cntf){
      float hv[19];
      #pragma unroll
      for (int n=0;n<19;++n) hv[n] = hS[n*256 + tid];
      float ag[19];
      #pragma unroll
      for (int n=0;n<19;++n) ag[n] = 0.f;
      #pragma unroll
      for (int e=0;e<36;++e) ag[EDST[e]] += hv[ESRC[e]];
      #pragma unroll
      for (int n=0;n<19;++n) aS[n*256 + tid] = ag[n];
    }
    __syncthreads();
  }
  const int lane = tid & 63, wv = tid >> 6;
  const int i0 = cg*8 + 2*wv, i1 = i0 + 1;
  float acc0[19], acc1[19];
  #pragma unroll
  for (int n=0;n<19;++n){ acc0[n]=0.f; acc1[n]=0.f; }
  if (lane < cnt4){
    const float4 wl0 = *((const float4*)(lw + i0*1000) + kq*64 + lane);
    const float4 wl1 = *((const float4*)(lw + i1*1000) + kq*64 + lane);
    const float4 wr0 = *((const float4*)(rw + i0*1000) + kq*64 + lane);
    const float4 wr1 = *((const float4*)(rw + i1*1000) + kq*64 + lane);
    const float4* h4 = (const float4*)hS;
    const float4* a4 = (const float4*)aS;
    #pragma unroll
    for (int n=0;n<19;++n){
      const float4 hv = h4[n*64+lane], av = a4[n*64+lane];
      acc0[n] = d4(wl0,av) + d4(wr0,hv);
      acc1[n] = d4(wl1,av) + d4(wr1,hv);
    }
  }
  #pragma unroll
  for (int n=0;n<19;++n){ acc0[n]=wredsum(acc0[n]); acc1[n]=wredsum(acc1[n]); }
  if (lane == 0){
    #pragma unroll
    for (int n=0;n<19;++n){
      pout[(kq*19+n)*1000 + i0] = acc0[n];
      pout[(kq*19+n)*1000 + i1] = acc1[n];
    }
  }
}

// ============================================================================
// GAT/GCN split matmul (unchanged)
// ============================================================================
template<int MODE>
DEV void gatmat_split(int blk, int tid, float* sm,
                      const float* __restrict__ hin, const float* __restrict__ pin,
                      const float* __restrict__ pbias,
                      const float* __restrict__ W, float* __restrict__ pout)
{
  const int cg = blk >> 2, kq = blk & 3;
  const int kb = kq*256;
  const int cntf = (kq < 3) ? 256 : 232;
  const int cnt4 = cntf >> 2;
  float* hS = sm;
  if (MODE == 2){
    for (int c = tid; c < 19*256; c += 256){
      const int n = c >> 8, j = c & 255;
      if (j < cntf){
        const int i = kb + j;
        const float v = pin[n*1000+i] + pin[(19+n)*1000+i] + pin[(38+n)*1000+i]
                      + pin[(57+n)*1000+i] + pbias[i];
        hS[c] = fmaxf(v, 0.f);
      }
    }
  } else {
    for (int c = tid; c < 19*64; c += 256){
      const int n = c >> 6, j = c & 63;
      if (j < cnt4)
        ((float4*)hS)[n*64 + j] = *(const float4*)(hin + n*1000 + kb + 4*j);
    }
  }
  __syncthreads();
  const int lane = tid & 63, wv = tid >> 6;
  const int i0 = cg*8 + 2*wv, i1 = i0 + 1;
  float acc0[19], acc1[19];
  #pragma unroll
  for (int n=0;n<19;++n){ acc0[n]=0.f; acc1[n]=0.f; }
  if (lane < cnt4){
    const float4 w0 = *((const float4*)(W + i0*1000) + kq*64 + lane);
    const float4 w1 = *((const float4*)(W + i1*1000) + kq*64 + lane);
    const float4* h4 = (const float4*)hS;
    #pragma unroll
    for (int n=0;n<19;++n){
      const float4 hv = h4[n*64+lane];
      acc0[n] = d4(w0,hv);
      acc1[n] = d4(w1,hv);
    }
  }
  #pragma unroll
  for (int n=0;n<19;++n){ acc0[n]=wredsum(acc0[n]); acc1[n]=wredsum(acc1[n]); }
  if (lane == 0){
    #pragma unroll
    for (int n=0;n<19;++n){
      pout[(kq*19+n)*1000 + i0] = acc0[n];
      pout[(kq*19+n)*1000 + i1] = acc1[n];
    }
  }
}

// ============================================================================
// k_alpha: ONE 1024-thread block. es/ed per-column products + 16-wave tree
// reduce, leaky-relu, segment softmax -> alpha[55].
// ============================================================================
__global__ __launch_bounds__(1024) void k_alpha(
    const float* __restrict__ ph, const float* __restrict__ as_,
    const float* __restrict__ ad_, float* __restrict__ alpha_out)
{
  __shared__ float red[608];  // 16 waves * 38
  __shared__ float s_es[19], s_ed[19], s_w[55], s_m[19], s_den[19];
  const int t = threadIdx.x, lane = t & 63, wv = t >> 6;
  const bool ok = t < 1000;
  const float asv = ok ? as_[t] : 0.f;
  const float adv = ok ? ad_[t] : 0.f;
  float es[19], ed[19];
  #pragma unroll
  for (int n=0;n<19;++n){
    float hh = 0.f;
    if (ok) hh = ph[n*1000+t] + ph[(19+n)*1000+t] + ph[(38+n)*1000+t] + ph[(57+n)*1000+t];
    es[n] = hh*asv; ed[n] = hh*adv;
  }
  #pragma unroll
  for (int n=0;n<19;++n){ es[n]=wredsum(es[n]); ed[n]=wredsum(ed[n]); }
  if (lane == 0){
    #pragma unroll
    for (int n=0;n<19;++n){ red[wv*38+n]=es[n]; red[wv*38+19+n]=ed[n]; }
  }
  __syncthreads();
  if (t < 38){
    float s = 0.f;
    #pragma unroll
    for (int w2=0; w2<16; ++w2) s += red[w2*38+t];
    if (t < 19) s_es[t] = s; else s_ed[t-19] = s;
  }
  __syncthreads();
  if (t < 55){
    float e = s_es[SSRC[t]] + s_ed[SDST[t]];
    s_w[t] = e > 0.f ? e : 0.2f*e;
  }
  __syncthreads();
  if (t < 19){
    float m = -1e30f;
    #pragma unroll
    for (int e=0;e<55;++e) if (SDST[e]==t) m = fmaxf(m, s_w[e]);
    float den = 0.f;
    #pragma unroll
    for (int e=0;e<55;++e) if (SDST[e]==t) den += expf(s_w[e]-m);
    s_m[t]=m; s_den[t]=den;
  }
  __syncthreads();
  if (t < 55) alpha_out[t] = expf(s_w[t]-s_m[SDST[t]]) / s_den[SDST[t]];
}

// ---- gagg: per-column GAT aggregation using precomputed alpha ----
DEV void gagg(int blk, int tid, float* sm, const float* __restrict__ ph,
              const float* __restrict__ alpha, const float* __restrict__ bias,
              float* __restrict__ hout)
{
  if (tid < 55) sm[tid] = alpha[tid];
  __syncthreads();
  const int i = blk*256 + tid;
  if (i < 1000){
    float hv[19];
    #pragma unroll
    for (int n=0;n<19;++n)
      hv[n] = ph[n*1000+i] + ph[(19+n)*1000+i] + ph[(38+n)*1000+i] + ph[(57+n)*1000+i];
    float acc[19];
    #pragma unroll
    for (int n=0;n<19;++n) acc[n]=0.f;
    #pragma unroll
    for (int e=0;e<55;++e) acc[SDST[e]] += sm[e]*hv[SSRC[e]];
    const float bi = bias[i];
    #pragma unroll
    for (int n=0;n<19;++n) hout[n*1000+i] = fmaxf(acc[n]+bi, 0.f);
  }
}

// =================== K1: conv1 + sage1a(+agg) + state MLP ===================
__global__ __launch_bounds__(256) void k_ac_1(
    const float* __restrict__ x, const float* __restrict__ c1w, const float* __restrict__ c1b,
    const float* __restrict__ xg, const float* __restrict__ s1alw, const float* __restrict__ s1alb,
    const float* __restrict__ s1arw,
    const float* __restrict__ stt, const float* __restrict__ fc2w, const float* __restrict__ fc2b,
    const float* __restrict__ fc3w, const float* __restrict__ fc3b,
    float* __restrict__ ws)
{
  const int b = blockIdx.x, t = threadIdx.x;
  if (b < 497){
    const int idx = b*256 + t;
    if (idx < 127008){
      const int oc = idx/3969, r = idx - oc*3969, oy = r/63, ox = r - oy*63;
      const float* wp = c1w + oc*25;
      float acc = c1b[oc];
      #pragma unroll
      for (int ky=0;ky<5;++ky){
        const int iy = oy*2 - 1 + ky;
        if ((unsigned)iy < 128u){
          #pragma unroll
          for (int kx=0;kx<5;++kx){
            const int ix = ox*2 - 1 + kx;
            if ((unsigned)ix < 128u) acc += x[iy*128+ix]*wp[ky*5+kx];
          }
        }
      }
      ws[WS_C1+idx] = fmaxf(acc, 0.f);
    }
  } else if (b < 501){
    const int i = (b-497)*256 + t;
    if (i < 1000){
      float xv[19];
      #pragma unroll
      for (int n=0;n<19;++n) xv[n] = xg[n];
      float ag[19];
      #pragma unroll
      for (int n=0;n<19;++n) ag[n]=0.f;
      #pragma unroll
      for (int e=0;e<36;++e) ag[EDST[e]] += xv[ESRC[e]];
      const float lwv=s1alw[i], lbv=s1alb[i], rwv=s1arw[i];
      float hc[19];
      #pragma unroll
      for (int n=0;n<19;++n){
        hc[n] = fmaxf(lwv*ag[n] + lbv + rwv*xv[n], 0.f);
        ws[WS_HA+n*1000+i] = hc[n];
      }
      #pragma unroll
      for (int n=0;n<19;++n){
        float a=0.f;
        #pragma unroll
        for (int e=0;e<36;++e) if (EDST[e]==n) a += hc[ESRC[e]];
        ws[WS_AGA+n*1000+i] = a;
      }
    }
  } else {
    __shared__ float s1[100];
    if (t < 100){
      float acc = fc2b[t];
      #pragma unroll
      for (int k=0;k<20;++k) acc += fc2w[t*20+k]*stt[k];
      s1[t] = acc;
    }
    __syncthreads();
    if (t < 100){
      float acc = fc3b[t];
      for (int k=0;k<100;++k) acc += fc3w[t*100+k]*s1[k];
      ws[WS_N2+t] = acc;
    }
  }
}

// =================== K2: conv2 (LDS) + sage1b-split ===================
__global__ __launch_bounds__(256) void k_ac_2(
    const float* __restrict__ c2w, const float* __restrict__ c2b,
    const float* __restrict__ s1blw, const float* __restrict__ s1blb, const float* __restrict__ s1brw,
    float* __restrict__ ws)
{
  __shared__ float sm[9728];
  const int b = blockIdx.x, t = threadIdx.x;
  if (b < 128){
    const int oc = b >> 2, q = b & 3;
    const int r0 = q*16;
    const int nout = (q < 3) ? 240 : 180;
    float* buf0 = sm; float* buf1 = sm + 4788;
    float rv[19];
    #pragma unroll
    for (int u=0; u<19; ++u){
      const int c = t + u*256; float v = 0.f;
      if (c < 4788){
        const int p = c/1197, r = c - p*1197, lr = r/63, xx = r - lr*63;
        const int iy = r0 + lr;
        if (iy < 63) v = ws[WS_C1 + p*3969 + iy*63 + xx];
      }
      rv[u] = v;
    }
    #pragma unroll
    for (int u=0; u<19; ++u){ const int c = t+u*256; if (c<4788) buf0[c]=rv[u]; }
    __syncthreads();
    const int oy_l = t/30, ox = t - oy_l*30;
    float acc = (t < nout) ? c2b[oc] : 0.f;
    for (int g=0; g<8; ++g){
      float* cur = (g&1) ? buf1 : buf0;
      if (g < 7){
        #pragma unroll
        for (int u=0; u<19; ++u){
          const int c = t + u*256; float v = 0.f;
          if (c < 4788){
            const int p = c/1197, r = c - p*1197, lr = r/63, xx = r - lr*63;
            const int iy = r0 + lr;
            if (iy < 63) v = ws[WS_C1 + (4*(g+1)+p)*3969 + iy*63 + xx];
          }
          rv[u] = v;
        }
      }
      if (t < nout){
        #pragma unroll
        for (int p=0;p<4;++p){
          const float* wp = c2w + (oc*32 + 4*g + p)*25;
          const float* ip = cur + p*1197 + (2*oy_l)*63 + 2*ox;
          #pragma unroll
          for (int ky=0;ky<5;++ky)
            #pragma unroll
            for (int kx=0;kx<5;++kx)
              acc += ip[ky*63+kx]*wp[ky*5+kx];
        }
      }
      if (g < 7){
        __syncthreads();
        float* nxt = (g&1) ? buf0 : buf1;
        #pragma unroll
        for (int u=0; u<19; ++u){ const int c = t+u*256; if (c<4788) nxt[c]=rv[u]; }
        __syncthreads();
      }
    }
    if (t < nout){
      const int oy = q*8 + oy_l;
      ws[WS_C2 + oc*900 + oy*30 + ox] = fmaxf(acc, 0.f);
    }
  } else {
    sage_split<0>(b-128, t, sm, ws+WS_HA, nullptr, nullptr, ws+WS_AGA, s1blw, s1brw, ws+WS_PB);
  }
}

// =================== K3: conv3 (LDS) + gat2mm-split ===================
__global__ __launch_bounds__(256) void k_ac_3(
    const float* __restrict__ c3w, const float* __restrict__ c3b,
    const float* __restrict__ s1blb, const float* __restrict__ g2w,
    float* __restrict__ ws)
{
  __shared__ float sm[7200];
  const int b = blockIdx.x, t = threadIdx.x;
  if (b < 32){
    const int oc = b;
    float* buf0 = sm; float* buf1 = sm + 3600;
    float rv[15];
    #pragma unroll
    for (int u=0; u<15; ++u){
      const int c = t + u*256;
      rv[u] = (c < 3600) ? ws[WS_C2 + c] : 0.f;
    }
    #pragma unroll
    for (int u=0; u<15; ++u){ const int c = t+u*256; if (c<3600) buf0[c]=rv[u]; }
    __syncthreads();
    const int oy = t/14, ox = t - oy*14;
    float acc = (t < 196) ? c3b[oc] : 0.f;
    for (int g=0; g<8; ++g){
      float* cur = (g&1) ? buf1 : buf0;
      if (g < 7){
        #pragma unroll
        for (int u=0; u<15; ++u){
          const int c = t + u*256;
          rv[u] = (c < 3600) ? ws[WS_C2 + (g+1)*3600 + c] : 0.f;
        }
      }
      if (t < 196){
        #pragma unroll
        for (int p=0;p<4;++p){
          const float* wp = c3w + (oc*32 + 4*g + p)*25;
          const float* ip = cur + p*900;
          #pragma unroll
          for (int ky=0;ky<5;++ky){
            const int iy = oy*2 - 1 + ky;
            if ((unsigned)iy < 30u){
              #pragma unroll
              for (int kx=0;kx<5;++kx){
                const int ix = ox*2 - 1 + kx;
                if ((unsigned)ix < 30u) acc += ip[iy*30+ix]*wp[ky*5+kx];
              }
            }
          }
        }
      }
      if (g < 7){
        __syncthreads();
        float* nxt = (g&1) ? buf0 : buf1;
        #pragma unroll
        for (int u=0; u<15; ++u){ const int c = t+u*256; if (c<3600) nxt[c]=rv[u]; }
        __syncthreads();
      }
    }
    if (t < 196) ws[WS_V + oc*196 + t] = acc;  // no relu on conv3
  } else {
    gatmat_split<2>(b-32, t, sm, nullptr, ws+WS_PB, s1blb, g2w, ws+WS_PH);
  }
}

// =================== K4: fc0 (K-split x2) + gat2 aggregation tail ===================
__global__ __launch_bounds__(256) void k_ac_4(
    const float* __restrict__ fc0w, const float* __restrict__ g2b,
    float* __restrict__ ws)
{
  __shared__ float sm[3136];
  const int b = blockIdx.x, t = threadIdx.x;
  if (b < 3000){
    const int rq = b >> 1, half = b & 1;
    const int lane = t & 63, wv = t >> 6;
    float4* smf4 = (float4*)sm;
    const float4* vsrc = (const float4*)(ws + WS_V) + half*784;
    for (int c = t; c < 784; c += 256) smf4[c] = vsrc[c];
    __syncthreads();
    const int row = rq*4 + wv;
    const float4* wr = (const float4*)(fc0w) + (size_t)row*1568 + half*784;
    float4 wreg[12];
    #pragma unroll
    for (int u=0; u<12; ++u) wreg[u] = wr[u*64 + lane];
    float4 wtail;
    if (lane < 16) wtail = wr[768 + lane];
    float acc = 0.f;
    #pragma unroll
    for (int u=0; u<12; ++u) acc += d4(wreg[u], smf4[u*64 + lane]);
    if (lane < 16) acc += d4(wtail, smf4[768 + lane]);
    acc = wredsum(acc);
    if (lane == 0){
      float* pout = ws + (half ? WS_FC0B : WS_FC0);
      pout[row] = acc;           // bias added in fc1 consumer
    }
  } else {
    gagg(b-3000, t, sm, ws+WS_PH, ws+WS_AL, g2b, ws+WS_HA);
  }
}

// =================== K5: fc1 (sums fc0 partials + bias) + sage3a-split ===================
__global__ __launch_bounds__(256) void k_ac_5(
    const float* __restrict__ fc1w, const float* __restrict__ fc1b,
    const float* __restrict__ fc0b,
    const float* __restrict__ s3alw, const float* __restrict__ s3arw,
    float* __restrict__ ws)
{
  __shared__ float sm[9728];
  const int b = blockIdx.x, t = threadIdx.x;
  if (b < 100){
    const int row = b, lane = t & 63, wv = t >> 6;
    const float4* wr = (const float4*)(fc1w + row*6000);
    const float4* p0 = (const float4*)(ws + WS_FC0);
    const float4* p1 = (const float4*)(ws + WS_FC0B);
    const float4* bb = (const float4*)fc0b;
    float acc = 0.f;
    #pragma unroll
    for (int u=0; u<6; ++u){
      const int j = t + u*256;
      if (j < 1500) acc += d4(wr[j], add4(p0[j], p1[j], bb[j]));
    }
    acc = wredsum(acc);
    if (lane == 0) sm[wv] = acc;
    __syncthreads();
    if (t == 0) ws[WS_N1+row] = sm[0]+sm[1]+sm[2]+sm[3] + fc1b[row];
  } else {
    sage_split<1>(b-100, t, sm, ws+WS_HA, nullptr, nullptr, nullptr, s3alw, s3arw, ws+WS_PB);
  }
}

// =================== K6: sage3b-split ===================
__global__ __launch_bounds__(256) void k_ac_6(
    const float* __restrict__ s3alb, const float* __restrict__ s3blw, const float* __restrict__ s3brw,
    float* __restrict__ ws)
{
  __shared__ float sm[9728];
  sage_split<2>(blockIdx.x, threadIdx.x, sm, nullptr, ws+WS_PB, s3alb, nullptr, s3blw, s3brw, ws+WS_PC);
}

// =================== K7: gat4mm-split ===================
__global__ __launch_bounds__(256) void k_ac_7(
    const float* __restrict__ s3blb, const float* __restrict__ g4w, float* __restrict__ ws)
{
  __shared__ float sm[4864];
  gatmat_split<2>(blockIdx.x, threadIdx.x, sm, nullptr, ws+WS_PC, s3blb, g4w, ws+WS_PH);
}

// =================== K8: gat4 aggregation (4 blocks) ===================
__global__ __launch_bounds__(256) void k_ac_8(
    const float* __restrict__ g4b, float* __restrict__ ws)
{
  __shared__ float sm[64];
  gagg(blockIdx.x, threadIdx.x, sm, ws+WS_PH, ws+WS_AL, g4b, ws+WS_HB);
}

// =================== K9: gcn-split ===================
__global__ __launch_bounds__(256) void k_ac_9(
    const float* __restrict__ gw, float* __restrict__ ws)
{
  __shared__ float sm[4864];
  gatmat_split<3>(blockIdx.x, threadIdx.x, sm, ws+WS_HB, nullptr, nullptr, gw, ws+WS_PB);
}

// =================== K10: gcn finish + node-mean -> gv ===================
__global__ __launch_bounds__(256) void k_ac_10(
    const float* __restrict__ gb, float* __restrict__ ws)
{
  const int i = blockIdx.x*256 + threadIdx.x;
  if (i < 1000){
    float c[19];
    #pragma unroll
    for (int m=0;m<19;++m) c[m] = 2.f*DINV[m]*DINV[m];
    #pragma unroll
    for (int e=0;e<36;++e) c[ESRC[e]] += DINV[ESRC[e]]*DINV[EDST[e]];
    float s = gb[i];
    #pragma unroll
    for (int m=0;m<19;++m){
      const float hh = ws[WS_PB + m*1000 + i] + ws[WS_PB + (19+m)*1000 + i]
                     + ws[WS_PB + (38+m)*1000 + i] + ws[WS_PB + (57+m)*1000 + i];
      s += (c[m]*(1.f/19.f))*hh;
    }
    ws[WS_GV+i] = s;
  }
}

// =================== K11: fcg (block-per-row) ===================
__global__ __launch_bounds__(256) void k_ac_11(
    const float* __restrict__ fcgw, const float* __restrict__ fcgb, float* __restrict__ ws)
{
  __shared__ float sm[4];
  const int b = blockIdx.x, t = threadIdx.x, lane = t & 63, wv = t >> 6;
  const float4* wr = (const float4*)(fcgw + b*1000);
  const float4* vr = (const float4*)(ws + WS_GV);
  float acc = (t < 250) ? d4(wr[t], vr[t]) : 0.f;
  acc = wredsum(acc);
  if (lane == 0) sm[wv] = acc;
  __syncthreads();
  if (t == 0) ws[WS_N3+b] = sm[0]+sm[1]+sm[2]+sm[3] + fcgb[b];
}

// =================== K12: head ===================
__global__ __launch_bounds__(512) void k_ac_head(
    const float* __restrict__ fc4w, const float* __restrict__ fc4b,
    const float* __restrict__ muw, const float* __restrict__ mub,
    const float* __restrict__ ls,  const float* __restrict__ crw, const float* __restrict__ crb,
    float* __restrict__ ws, float* __restrict__ out)
{
  __shared__ float f[300];
  __shared__ float mnmx[6];
  __shared__ float feats[200];
  const int t = threadIdx.x, lane = t & 63, wv = t >> 6;
  if (t < 100)       f[t] = ws[WS_N1 + t];
  else if (t < 200)  f[t] = ws[WS_N2 + t - 100];
  else if (t < 300)  f[t] = ws[WS_N3 + t - 200];
  if (t >= 300 && t < 312) out[t - 288] = expf(ls[t-300]);   // sigma
  __syncthreads();
  if (wv < 3){
    const int base = wv*100;
    const float v  = f[base + lane];
    const float v2 = (lane < 36) ? f[base + 64 + lane] : v;
    float mn = fminf(v, v2), mx = fmaxf(v, v2);
    #pragma unroll
    for (int o=32;o;o>>=1){ mn = fminf(mn, __shfl_xor(mn,o)); mx = fmaxf(mx, __shfl_xor(mx,o)); }
    if (lane == 0){ mnmx[wv*2]=mn; mnmx[wv*2+1]=mx; }
  }
  __syncthreads();
  if (t < 300){
    const int c = t/100;
    f[t] = (f[t]-mnmx[c*2])/(mnmx[c*2+1]-mnmx[c*2]);
  }
  __syncthreads();
  for (int rr=0; rr<25; ++rr){
    const int row = wv*25 + rr;
    const float* wp = fc4w + row*300;
    float acc = 0.f;
    #pragma unroll
    for (int it=0; it<5; ++it){
      const int k = it*64 + lane;
      if (k < 300) acc += wp[k]*f[k];
    }
    acc = wredsum(acc);
    if (lane == 0) feats[row] = acc + fc4b[row];
  }
  __syncthreads();
  // mu rows (12) + value: wave-parallel
  #pragma unroll
  for (int rr=0; rr<2; ++rr){
    const int row = wv + rr*8;
    if (row < 12){
      const float* wp = muw + row*200;
      float a = 0.f;
      #pragma unroll
      for (int it=0; it<4; ++it){
        const int k = it*64 + lane;
        if (k < 200) a += wp[k]*feats[k];
      }
      a = wredsum(a);
      if (lane == 0) out[row] = tanhf(a + mub[row]);
    } else if (rr == 1 && wv == 4){
      float a = 0.f;
      #pragma unroll
      for (int it=0; it<4; ++it){
        const int k = it*64 + lane;
        if (k < 200) a += crw[k]*feats[k];
      }
      a = wredsum(a);
      if (lane == 0) out[24] = a + crb[0];
    }
  }
}

extern "C" void kernel_launch(void* const* d_in, const int* in_sizes, int n_in,
                              void* d_out, int out_size, void* d_ws, size_t ws_size,
                              hipStream_t stream)
{
  (void)in_sizes; (void)n_in; (void)out_size; (void)ws_size;
  const float* x     = (const float*)d_in[0];
  const float* stt   = (const float*)d_in[1];
  const float* xg    = (const float*)d_in[2];
  const float* c1w   = (const float*)d_in[3];
  const float* c1b   = (const float*)d_in[4];
  const float* c2w   = (const float*)d_in[5];
  const float* c2b   = (const float*)d_in[6];
  const float* c3w   = (const float*)d_in[7];
  const float* c3b   = (const float*)d_in[8];
  const float* fc0w  = (const float*)d_in[9];
  const float* fc0b  = (const float*)d_in[10];
  const float* fc1w  = (const float*)d_in[11];
  const float* fc1b  = (const float*)d_in[12];
  const float* fc2w  = (const float*)d_in[13];
  const float* fc2b  = (const float*)d_in[14];
  const float* fc3w  = (const float*)d_in[15];
  const float* fc3b  = (const float*)d_in[16];
  const float* s1alw = (const float*)d_in[17];
  const float* s1alb = (const float*)d_in[18];
  const float* s1arw = (const float*)d_in[19];
  const float* s1blw = (const float*)d_in[20];
  const float* s1blb = (const float*)d_in[21];
  const float* s1brw = (const float*)d_in[22];
  const float* g2w   = (const float*)d_in[23];
  const float* g2as  = (const float*)d_in[24];
  const float* g2ad  = (const float*)d_in[25];
  const float* g2b   = (const float*)d_in[26];
  const float* s3alw = (const float*)d_in[27];
  const float* s3alb = (const float*)d_in[28];
  const float* s3arw = (const float*)d_in[29];
  const float* s3blw = (const float*)d_in[30];
  const float* s3blb = (const float*)d_in[31];
  const float* s3brw = (const float*)d_in[32];
  const float* g4w   = (const float*)d_in[33];
  const float* g4as  = (const float*)d_in[34];
  const float* g4ad  = (const float*)d_in[35];
  const float* g4b   = (const float*)d_in[36];
  const float* gcnw  = (const float*)d_in[37];
  const float* gcnb  = (const float*)d_in[38];
  const float* fcgw  = (const float*)d_in[39];
  const float* fcgb  = (const float*)d_in[40];
  const float* fc4w  = (const float*)d_in[41];
  const float* fc4b  = (const float*)d_in[42];
  const float* muw   = (const float*)d_in[43];
  const float* mub   = (const float*)d_in[44];
  const float* lsig  = (const float*)d_in[45];
  const float* crw   = (const float*)d_in[46];
  const float* crb   = (const float*)d_in[47];
  float* ws  = (float*)d_ws;
  float* out = (float*)d_out;

  k_ac_1 <<<dim3(502), dim3(256), 0, stream>>>(x, c1w, c1b, xg, s1alw, s1alb, s1arw,
                                               stt, fc2w, fc2b, fc3w, fc3b, ws);
  k_ac_2 <<<dim3(628), dim3(256), 0, stream>>>(c2w, c2b, s1blw, s1blb, s1brw, ws);
  k_ac_3 <<<dim3(532), dim3(256), 0, stream>>>(c3w, c3b, s1blb, g2w, ws);
  k_alpha<<<dim3(1), dim3(1024), 0, stream>>>(ws+WS_PH, g2as, g2ad, ws+WS_AL);
  k_ac_4 <<<dim3(3004), dim3(256), 0, stream>>>(fc0w, g2b, ws);
  k_ac_5 <<<dim3(600), dim3(256), 0, stream>>>(fc1w, fc1b, fc0b, s3alw, s3arw, ws);
  k_ac_6 <<<dim3(500), dim3(256), 0, stream>>>(s3alb, s3blw, s3brw, ws);
  k_ac_7 <<<dim3(500), dim3(256), 0, stream>>>(s3blb, g4w, ws);
  k_alpha<<<dim3(1), dim3(1024), 0, stream>>>(ws+WS_PH, g4as, g4ad, ws+WS_AL);
  k_ac_8 <<<dim3(4),   dim3(256), 0, stream>>>(g4b, ws);
  k_ac_9 <<<dim3(500), dim3(256), 0, stream>>>(gcnw, ws);
  k_ac_10<<<dim3(4),   dim3(256), 0, stream>>>(gcnb, ws);
  k_ac_11<<<dim3(100), dim3(256), 0, stream>>>(fcgw, fcgb, ws);
  k_ac_head<<<dim3(1), dim3(512), 0, stream>>>(fc4w, fc4b, muw, mub, lsig, crw, crb, ws, out);
}